// Round 1
// baseline (438.721 us; speedup 1.0000x reference)
//
#include <hip/hip_runtime.h>

// BuildingModule: B=8192 sequential chains, T=1024 steps, u:(B,T,8) f32, out:(B,T,3) f32.
//
// R4: two changes vs R3 (413.9 us), both targeting exposed latency at 1 wave/SIMD:
//
// (1) Algebraic chain compression. Using i_k*X_k = 1 + O(ulp):
//       d12*X1 = i0*X1 - 1;  d12*X0 = 1 - i1*X0;  d23*X2 = i1*X2 - 1;  d23*X1 = 1 - i2*X1
//     so every update becomes
//       z_k = fmaf(i_k, p_k, G'_k),  p_k = fmaf(F, X_neighbor, E_k)
//     with the row-independent -F constants folded into G' at pre-fold time.
//     p_k depends only on X (parallel with the rcp) -> per-step critical path is
//     rcp || fma -> fma -> exp2 -> mul (~26 cy vs ~50 cy in R3), and ~3 fewer
//     VALU ops/step (no d12/d23 subs, no F*d muls).
//
// (2) LDS round-trip pipelined one block ahead. Body j: fold+write block j+1,
//     prefetch global block j+3, ISSUE the 16 broadcast reads for j+1 into a
//     second register set, THEN compute block j from the first set. The lgkm
//     wait for a set is covered by a full 8-step compute phase instead of
//     stalling ~150 cy at every block boundary.
//
// Wave-synchronous LDS broadcast (8 lanes/chain inside one wave, in-order DS
// pipe) -- no barriers, same XOR-swizzled conflict-free slot layout as R3.

#if __has_builtin(__builtin_amdgcn_exp2f)
#define EXP2F(x) __builtin_amdgcn_exp2f(x)
#else
#define EXP2F(x) __expf((x) * 0.69314718056f)
#endif

namespace {
constexpr int T = 1024;
constexpr int NBLK = T / 8;           // 128 blocks of 8 rows
constexpr float LOG2E = 1.4426950408889634f;
constexpr int CH_STRIDE = 68;         // floats per chain LDS region (8 rows * 8 + 4 pad)
}

__global__ __launch_bounds__(256, 1) void bm_fwd(
    const float* __restrict__ x0p,   // (B,3)
    const float* __restrict__ up,    // (B,T,8)
    const float* __restrict__ lamp,  // (14)
    float* __restrict__ outp)        // (B,T,3)
{
    // 32 chains/WG * 272B, XOR-swizzled row slots: row r of chain g -> slot (r^g).
    __shared__ float lds[32 * CH_STRIDE];

    const int tid   = blockIdx.x * 256 + threadIdx.x;
    const int chain = tid >> 3;
    const int phase = tid & 7;
    const int g     = (threadIdx.x >> 3) & 7;   // group within wave
    float* __restrict__ region = lds + (threadIdx.x >> 3) * CH_STRIDE;
    float* __restrict__ wslot  = region + ((phase ^ g) << 3);

    // lam -> exponentials (uniform; precise expf once per thread)
    float e[14];
#pragma unroll
    for (int i = 0; i < 14; ++i) e[i] = expf(lamp[i]);
    const float e12 = e[0], e23 = e[1];

    // H/C in log2 domain, folded into every coefficient
    const float hc0 = (60.0f / 10665991.0f) * LOG2E;
    const float hc1 = (60.0f / 27000000.0f) * LOG2E;
    const float hc2 = (60.0f / 7953253.0f) * LOG2E;
    const float F12_0 = hc0 * e12, F12_1 = hc1 * e12;
    const float F23_1 = hc1 * e23, F23_2 = hc2 * e23;
    const float hce0 = hc0 * e[2],  hce1 = hc1 * e[3],  hce2 = hc2 * e[4];
    const float ss0  = hc0 * e[5],  ss1  = hc1 * e[6],  ss2  = hc2 * e[7];
    const float sh0  = hc0 * e[8],  sh1  = hc1 * e[9],  sh2  = hc2 * e[10];
    const float sc0  = hc0 * e[11], sc1  = hc1 * e[12], sc2  = hc2 * e[13];
    // -F constants folded into the G' bias (algebra change (1))
    const float g0c = -hce0 - F12_0;
    const float g1c = -hce1 - F12_1 - F23_1;
    const float g2c = -hce2 - F23_2;

    float X0 = x0p[3 * chain + 0];
    float X1 = x0p[3 * chain + 1];
    float X2 = x0p[3 * chain + 2];

    const float4* __restrict__ ub = (const float4*)(up + (size_t)chain * (T * 8));
    float* __restrict__ ob = outp + (size_t)chain * (T * 3);

    // pre-fold my row into 6 floats and write to my LDS slot; returns my u0
    auto fold_write = [&](const float4& r0, const float4& r1) -> float {
        const float E0 = hce0 * r0.x, E1 = hce1 * r0.x, E2 = hce2 * r0.x;
        const float G0 = fmaf(sc0, r1.y, fmaf(sh0, r0.z, fmaf(ss0, r0.y, g0c)));
        const float G1 = fmaf(sc1, r1.z, fmaf(sh1, r0.w, fmaf(ss1, r0.y, g1c)));
        const float G2 = fmaf(sc2, r1.w, fmaf(sh2, r1.x, fmaf(ss2, r0.y, g2c)));
        *(float4*)wslot       = make_float4(E0, E1, E2, G0);
        *(float2*)(wslot + 4) = make_float2(G1, G2);
        return r0.x;
    };

    // hoisted conflict-free broadcast reads of all 8 rows into a register set
    auto issue_reads = [&](float4 (&A)[8], float2 (&Bv)[8]) {
#pragma unroll
        for (int i = 0; i < 8; ++i) {
            float* p = region + ((i ^ g) << 3);
            A[i] = *(float4*)p;
            Bv[i] = *(float2*)(p + 4);
        }
    };

    // 8 steps of block j from a register set; store my output row
    auto compute = [&](int j, const float4 (&A)[8], const float2 (&Bv)[8],
                       float myu0) {
        float O0 = 0.0f, O1 = 0.0f, O2 = 0.0f;
#pragma unroll
        for (int i = 0; i < 8; ++i) {
            if (phase == i) { O0 = X0; O1 = X1; O2 = X2; }   // state BEFORE row 8j+i
            const float i0 = __builtin_amdgcn_rcpf(X0);
            const float i1 = __builtin_amdgcn_rcpf(X1);
            const float i2 = __builtin_amdgcn_rcpf(X2);
            // p_k parallel with the rcp (depend only on X)
            const float p0 = fmaf(F12_0, X1, A[i].x);
            const float p1 = fmaf(F12_1, X0, fmaf(F23_1, X2, A[i].y));
            const float p2 = fmaf(F23_2, X1, A[i].z);
            const float z0 = fmaf(i0, p0, A[i].w);   // A.w = G0'
            const float z1 = fmaf(i1, p1, Bv[i].x);  // Bv.x = G1'
            const float z2 = fmaf(i2, p2, Bv[i].y);  // Bv.y = G2'
            X0 *= EXP2F(z0);
            X1 *= EXP2F(z1);
            X2 *= EXP2F(z2);
        }
        const bool bad = (myu0 < 1e-6f) && !((j == 0) & (phase == 0));
        float3 o;
        o.x = bad ? -1.0f : O0;
        o.y = bad ? -1.0f : O1;
        o.z = bad ? -1.0f : O2;
        *(float3*)(ob + (size_t)((j << 3) + phase) * 3) = o;
    };

    float4 bAa[8], bAb[8];
    float2 bBa[8], bBb[8];
    float4 rE0, rE1, rO0, rO1;   // raw u rows in flight (even/odd bodies)
    float myu0A, myu0B;

    // prologue: block 0 folded+read into set A; blocks 1,2 in flight in regs
    {
        const float4* s0 = ub + (size_t)((0 + phase) * 2);   // block 0 (wait target)
        float4 t0 = s0[0], t1 = s0[1];
        const float4* s1 = ub + (size_t)((8 + phase) * 2);   // block 1
        rE0 = s1[0]; rE1 = s1[1];
        const float4* s2 = ub + (size_t)((16 + phase) * 2);  // block 2
        rO0 = s2[0]; rO1 = s2[1];
        myu0A = fold_write(t0, t1);
        issue_reads(bAa, bBa);
    }

    // invariant entering the even body at j: rE = block j+1, rO = block j+2,
    // set A holds block j, myu0A is my u0 for block j.
    for (int j = 0; j < NBLK; j += 2) {
        // even body: prepare set B (block j+1), compute block j from set A
        myu0B = fold_write(rE0, rE1);                         // block j+1
        {
            const int jj = (j + 3 < NBLK) ? (j + 3) : (NBLK - 1);
            const float4* s = ub + (size_t)(((jj << 3) + phase) * 2);
            rE0 = s[0]; rE1 = s[1];                           // block j+3
        }
        issue_reads(bAb, bBb);                                // reads for j+1
        compute(j, bAa, bBa, myu0A);                          // lgkm covered by prev body

        // odd body: prepare set A (block j+2), compute block j+1 from set B
        myu0A = fold_write(rO0, rO1);                         // block j+2 (tail: clamped dup, unused)
        {
            const int jj = (j + 4 < NBLK) ? (j + 4) : (NBLK - 1);
            const float4* s = ub + (size_t)(((jj << 3) + phase) * 2);
            rO0 = s[0]; rO1 = s[1];                           // block j+4
        }
        issue_reads(bAa, bBa);                                // reads for j+2
        compute(j + 1, bAb, bBb, myu0B);
    }
}

extern "C" void kernel_launch(void* const* d_in, const int* in_sizes, int n_in,
                              void* d_out, int out_size, void* d_ws, size_t ws_size,
                              hipStream_t stream) {
    const float* x0  = (const float*)d_in[0];   // (B,3)
    const float* u   = (const float*)d_in[1];   // (B,T,8)
    const float* lam = (const float*)d_in[2];   // (14)
    float* out = (float*)d_out;                 // (B,T,3)

    const int B = in_sizes[0] / 3;              // 8192
    const int threads = B * 8;                  // 8 lanes per chain
    dim3 grid(threads / 256), block(256);
    hipLaunchKernelGGL(bm_fwd, grid, block, 0, stream, x0, u, lam, out);
}